// Round 10
// baseline (80.754 us; speedup 1.0000x reference)
//
#include <hip/hip_runtime.h>
#include <math.h>

typedef __attribute__((ext_vector_type(8))) short short8;
typedef __attribute__((ext_vector_type(4))) float f32x4;

#define SCALE 0.08838834764831845f   // 1/sqrt(128)

// ws byte offsets (total 49408)
#define WS_W1H 0
#define WS_W1L 8192
#define WS_W2H 16384
#define WS_W2L 24576
#define WS_GH  32768
#define WS_GL  40960
#define WS_g   49152

// LDS: W1T hi/lo 16K | G->Zk hi/lo 16K | 4 waves x 2 H planes x 4K | ck 256B
#define L_W1T 0
#define L_G   16384
#define L_XH  32768
#define L_CK  65536
#define LDS_BYTES 65792

__device__ __forceinline__ unsigned f2bf(float f) {   // RNE (precompute only)
    unsigned u = __float_as_uint(f);
    return (u + 0x7fffu + ((u >> 16) & 1u)) >> 16;
}
__device__ __forceinline__ float bfhi(unsigned h) { return __uint_as_float(h << 16); }
__device__ __forceinline__ f32x4 mk4(float v) { f32x4 r = {v, v, v, v}; return r; }
// interleaved word: (lo16 << 16) | hi16, trunc split
__device__ __forceinline__ unsigned packHL(float v) {
    unsigned u = __float_as_uint(v);
    float res = v - __uint_as_float(u & 0xffff0000u);
    return (__float_as_uint(res) & 0xffff0000u) | (u >> 16);
}
union U4S8 { uint4 u4; unsigned u[4]; short8 s; };

// dst_h = (hi16(b)<<16)|hi16(a) ; dst_l = same for trunc residuals
#define PACKPAIR(DH, DL, A, B) do {                                     \
    unsigned _ua = __float_as_uint(A), _ub = __float_as_uint(B);        \
    (DH) = __builtin_amdgcn_perm(_ub, _ua, 0x07060302u);                \
    float _ra = (A) - __uint_as_float(_ua & 0xffff0000u);               \
    float _rb = (B) - __uint_as_float(_ub & 0xffff0000u);               \
    (DL) = __builtin_amdgcn_perm(__float_as_uint(_rb),                  \
                                 __float_as_uint(_ra), 0x07060302u);    \
} while (0)

#define RELU4(ACC) do {                                                  \
    _Pragma("unroll")                                                    \
    for (int _n = 0; _n < 4; ++_n) {                                     \
        _Pragma("unroll")                                                \
        for (int _r = 0; _r < 4; ++_r)                                   \
            (ACC)[_n][_r] = fmaxf((ACC)[_n][_r], 0.f);                   \
    }                                                                    \
} while (0)

// ---- PE directly into MFMA A-fragments (identity feature layout) ----
// quarter g holds k = 8g+e (ks=0) and 32+8g+e (ks=1); features:
// 0-2 loc | 3+6i+c sin_i | 6+6i+c cos_i (f_i = 1.5*2^i) | 39-41 dir | 42 bias | 43+ 0
__device__ __forceinline__ void pe_frags(short8& Ah0, short8& Al0, short8& Ah1, short8& Al1,
                                         const float* __restrict__ pose, int g) {
    float2 r0 = *(const float2*)(pose + 2);
    float2 r1 = *(const float2*)(pose + 6);
    float2 r2 = *(const float2*)(pose + 10);
    const float Lx = r0.y, Ly = r1.y, Lz = r2.y;
    float F0[8], F1[8];
#pragma unroll
    for (int e = 0; e < 8; ++e) F1[e] = 0.f;
    if (g == 0) {          // p0-7: loc, s0, c0x, c0y | p32-39: c4z, s5, c5, dirx
        float sx, cx, sy, cy, sz, cz;
        __sincosf(1.5f * Lx, &sx, &cx);
        __sincosf(1.5f * Ly, &sy, &cy);
        __sincosf(1.5f * Lz, &sz, &cz);
        F0[0] = Lx; F0[1] = Ly; F0[2] = Lz;
        F0[3] = sx; F0[4] = sy; F0[5] = sz; F0[6] = cx; F0[7] = cy;
        float s4x, c4x, s4y, c4y, s4z, c4z;
        __sincosf(24.f * Lx, &s4x, &c4x);
        __sincosf(24.f * Ly, &s4y, &c4y);
        __sincosf(24.f * Lz, &s4z, &c4z);
        F1[0] = c4z;
        F1[1] = 2.f * s4x * c4x; F1[2] = 2.f * s4y * c4y; F1[3] = 2.f * s4z * c4z;
        F1[4] = fmaf(c4x, c4x, -s4x * s4x);
        F1[5] = fmaf(c4y, c4y, -s4y * s4y);
        F1[6] = fmaf(c4z, c4z, -s4z * s4z);
        F1[7] = r0.x;
    } else if (g == 1) {   // p8-15: c0z, s1, c1, s2x | p40-47: diry, dirz, 1, 0...
        float s0z, c0z;
        __sincosf(1.5f * Lz, &s0z, &c0z);
        float sx, cx, sy, cy, sz, cz;
        __sincosf(3.f * Lx, &sx, &cx);
        __sincosf(3.f * Ly, &sy, &cy);
        __sincosf(3.f * Lz, &sz, &cz);
        F0[0] = c0z;
        F0[1] = sx; F0[2] = sy; F0[3] = sz; F0[4] = cx; F0[5] = cy; F0[6] = cz;
        F0[7] = 2.f * sx * cx;
        F1[0] = r1.x; F1[1] = r2.x; F1[2] = 1.0f;
    } else if (g == 2) {   // p16-23: s2y, s2z, c2, s3 | zeros
        float sx, cx, sy, cy, sz, cz;
        __sincosf(6.f * Lx, &sx, &cx);
        __sincosf(6.f * Ly, &sy, &cy);
        __sincosf(6.f * Lz, &sz, &cz);
        F0[0] = sy; F0[1] = sz; F0[2] = cx; F0[3] = cy; F0[4] = cz;
        F0[5] = 2.f * sx * cx; F0[6] = 2.f * sy * cy; F0[7] = 2.f * sz * cz;
    } else {               // p24-31: c3, s4, c4x, c4y | zeros
        float sx, cx, sy, cy, sz, cz;
        __sincosf(12.f * Lx, &sx, &cx);
        __sincosf(12.f * Ly, &sy, &cy);
        __sincosf(12.f * Lz, &sz, &cz);
        F0[0] = cx; F0[1] = cy; F0[2] = cz;
        F0[3] = 2.f * sx * cx; F0[4] = 2.f * sy * cy; F0[5] = 2.f * sz * cz;
        F0[6] = fmaf(cx, cx, -sx * sx);
        F0[7] = fmaf(cy, cy, -sy * sy);
    }
    U4S8 th, tl;
#pragma unroll
    for (int i = 0; i < 4; ++i) PACKPAIR(th.u[i], tl.u[i], F0[2 * i], F0[2 * i + 1]);
    Ah0 = th.s; Al0 = tl.s;
#pragma unroll
    for (int i = 0; i < 4; ++i) PACKPAIR(th.u[i], tl.u[i], F1[2 * i], F1[2 * i + 1]);
    Ah1 = th.s; Al1 = tl.s;
}

// A-frags (both ks) from interleaved H plane: 4 b128 reads + 16 v_perm (R7-proven)
#define READ_A(H, Ah0, Al0, Ah1, Al1) do {                              \
    uint4 _a = *(const uint4*)((H) + hb00);                             \
    uint4 _b = *(const uint4*)((H) + hb01);                             \
    uint4 _c = *(const uint4*)((H) + hb10);                             \
    uint4 _d = *(const uint4*)((H) + hb11);                             \
    U4S8 _t;                                                            \
    _t.u[0] = __builtin_amdgcn_perm(_a.y, _a.x, 0x05040100u);           \
    _t.u[1] = __builtin_amdgcn_perm(_a.w, _a.z, 0x05040100u);           \
    _t.u[2] = __builtin_amdgcn_perm(_b.y, _b.x, 0x05040100u);           \
    _t.u[3] = __builtin_amdgcn_perm(_b.w, _b.z, 0x05040100u);           \
    Ah0 = _t.s;                                                         \
    _t.u[0] = __builtin_amdgcn_perm(_a.y, _a.x, 0x07060302u);           \
    _t.u[1] = __builtin_amdgcn_perm(_a.w, _a.z, 0x07060302u);           \
    _t.u[2] = __builtin_amdgcn_perm(_b.y, _b.x, 0x07060302u);           \
    _t.u[3] = __builtin_amdgcn_perm(_b.w, _b.z, 0x07060302u);           \
    Al0 = _t.s;                                                         \
    _t.u[0] = __builtin_amdgcn_perm(_c.y, _c.x, 0x05040100u);           \
    _t.u[1] = __builtin_amdgcn_perm(_c.w, _c.z, 0x05040100u);           \
    _t.u[2] = __builtin_amdgcn_perm(_d.y, _d.x, 0x05040100u);           \
    _t.u[3] = __builtin_amdgcn_perm(_d.w, _d.z, 0x05040100u);           \
    Ah1 = _t.s;                                                         \
    _t.u[0] = __builtin_amdgcn_perm(_c.y, _c.x, 0x07060302u);           \
    _t.u[1] = __builtin_amdgcn_perm(_c.w, _c.z, 0x07060302u);           \
    _t.u[2] = __builtin_amdgcn_perm(_d.y, _d.x, 0x07060302u);           \
    _t.u[3] = __builtin_amdgcn_perm(_d.w, _d.z, 0x07060302u);           \
    Al1 = _t.s;                                                         \
} while (0)

// single-tile hi/lo gemm, B planes in LDS (hi @BP, lo @BP+8192)
#define GEMM6_LDS(ACC, Ah0, Al0, Ah1, Al1, BP) do {                     \
    _Pragma("unroll")                                                   \
    for (int _nt = 0; _nt < 4; ++_nt) {                                 \
        const char* _b = (BP) + _nt * 2048;                             \
        short8 _bh0 = *(const short8*)(_b + aoff0);                     \
        short8 _bl0 = *(const short8*)(_b + 8192 + aoff0);              \
        short8 _bh1 = *(const short8*)(_b + aoff1);                     \
        short8 _bl1 = *(const short8*)(_b + 8192 + aoff1);              \
        f32x4 _x = (ACC)[_nt];                                          \
        _x = __builtin_amdgcn_mfma_f32_16x16x32_bf16(Ah0, _bh0, _x, 0, 0, 0); \
        _x = __builtin_amdgcn_mfma_f32_16x16x32_bf16(Ah0, _bl0, _x, 0, 0, 0); \
        _x = __builtin_amdgcn_mfma_f32_16x16x32_bf16(Al0, _bh0, _x, 0, 0, 0); \
        _x = __builtin_amdgcn_mfma_f32_16x16x32_bf16(Ah1, _bh1, _x, 0, 0, 0); \
        _x = __builtin_amdgcn_mfma_f32_16x16x32_bf16(Ah1, _bl1, _x, 0, 0, 0); \
        _x = __builtin_amdgcn_mfma_f32_16x16x32_bf16(Al1, _bh1, _x, 0, 0, 0); \
        (ACC)[_nt] = _x;                                                \
    }                                                                   \
} while (0)

// pair gemm: B-frags read ONCE, feed both tiles (12 MFMA per 4 loads)
#define GEMM6_LDS_PAIR(ACCA, Aa0, Aal0, Aa1, Aal1, ACCB, Bb0, Bbl0, Bb1, Bbl1, BP) do { \
    _Pragma("unroll")                                                   \
    for (int _nt = 0; _nt < 4; ++_nt) {                                 \
        const char* _b = (BP) + _nt * 2048;                             \
        short8 _bh0 = *(const short8*)(_b + aoff0);                     \
        short8 _bl0 = *(const short8*)(_b + 8192 + aoff0);              \
        short8 _bh1 = *(const short8*)(_b + aoff1);                     \
        short8 _bl1 = *(const short8*)(_b + 8192 + aoff1);              \
        f32x4 _x = (ACCA)[_nt];                                         \
        _x = __builtin_amdgcn_mfma_f32_16x16x32_bf16(Aa0, _bh0, _x, 0, 0, 0); \
        _x = __builtin_amdgcn_mfma_f32_16x16x32_bf16(Aa0, _bl0, _x, 0, 0, 0); \
        _x = __builtin_amdgcn_mfma_f32_16x16x32_bf16(Aal0, _bh0, _x, 0, 0, 0); \
        _x = __builtin_amdgcn_mfma_f32_16x16x32_bf16(Aa1, _bh1, _x, 0, 0, 0); \
        _x = __builtin_amdgcn_mfma_f32_16x16x32_bf16(Aa1, _bl1, _x, 0, 0, 0); \
        _x = __builtin_amdgcn_mfma_f32_16x16x32_bf16(Aal1, _bh1, _x, 0, 0, 0); \
        (ACCA)[_nt] = _x;                                               \
        f32x4 _y = (ACCB)[_nt];                                         \
        _y = __builtin_amdgcn_mfma_f32_16x16x32_bf16(Bb0, _bh0, _y, 0, 0, 0); \
        _y = __builtin_amdgcn_mfma_f32_16x16x32_bf16(Bb0, _bl0, _y, 0, 0, 0); \
        _y = __builtin_amdgcn_mfma_f32_16x16x32_bf16(Bbl0, _bh0, _y, 0, 0, 0); \
        _y = __builtin_amdgcn_mfma_f32_16x16x32_bf16(Bb1, _bh1, _y, 0, 0, 0); \
        _y = __builtin_amdgcn_mfma_f32_16x16x32_bf16(Bb1, _bl1, _y, 0, 0, 0); \
        _y = __builtin_amdgcn_mfma_f32_16x16x32_bf16(Bbl1, _bh1, _y, 0, 0, 0); \
        (ACCB)[_nt] = _y;                                               \
    }                                                                   \
} while (0)

// hi/lo gemm, B fragments in registers (W2T)
#define GEMM6_REG(ACC, Ah0, Al0, Ah1, Al1, Bh, Bl) do {                 \
    _Pragma("unroll")                                                   \
    for (int _nt = 0; _nt < 4; ++_nt) {                                 \
        f32x4 _x = (ACC)[_nt];                                          \
        _x = __builtin_amdgcn_mfma_f32_16x16x32_bf16(Ah0, (Bh)[0][_nt], _x, 0, 0, 0); \
        _x = __builtin_amdgcn_mfma_f32_16x16x32_bf16(Ah0, (Bl)[0][_nt], _x, 0, 0, 0); \
        _x = __builtin_amdgcn_mfma_f32_16x16x32_bf16(Al0, (Bh)[0][_nt], _x, 0, 0, 0); \
        _x = __builtin_amdgcn_mfma_f32_16x16x32_bf16(Ah1, (Bh)[1][_nt], _x, 0, 0, 0); \
        _x = __builtin_amdgcn_mfma_f32_16x16x32_bf16(Ah1, (Bl)[1][_nt], _x, 0, 0, 0); \
        _x = __builtin_amdgcn_mfma_f32_16x16x32_bf16(Al1, (Bh)[1][_nt], _x, 0, 0, 0); \
        (ACC)[_nt] = _x;                                                \
    }                                                                   \
} while (0)

// C-tile -> interleaved H plane (16 b32 writes), swizzled
#define STORE_H(H, ACC) do {                                            \
    _Pragma("unroll")                                                   \
    for (int _nt = 0; _nt < 4; ++_nt) {                                 \
        _Pragma("unroll")                                               \
        for (int _r = 0; _r < 4; ++_r) {                                \
            int _row = q4 + _r;                                         \
            int _byte = _row * 256 + ((((l15 + 16 * _nt) << 2)) ^ ((_row & 7) << 4)); \
            *(unsigned*)((H) + _byte) = packHL((ACC)[_nt][_r]);         \
        }                                                               \
    }                                                                   \
} while (0)

#define SOFTMAX_STORE(ACC, QOFF) do {                                   \
    _Pragma("unroll")                                                   \
    for (int _r = 0; _r < 4; ++_r) {                                    \
        float _m = fmaxf(fmaxf((ACC)[0][_r], (ACC)[1][_r]),             \
                         fmaxf((ACC)[2][_r], (ACC)[3][_r]));            \
        _m = fmaxf(_m, __shfl_xor(_m, 1));                              \
        _m = fmaxf(_m, __shfl_xor(_m, 2));                              \
        _m = fmaxf(_m, __shfl_xor(_m, 4));                              \
        _m = fmaxf(_m, __shfl_xor(_m, 8));                              \
        float _e0 = __expf(((ACC)[0][_r] - _m) * SCALE);                \
        float _e1 = __expf(((ACC)[1][_r] - _m) * SCALE);                \
        float _e2 = __expf(((ACC)[2][_r] - _m) * SCALE);                \
        float _e3 = __expf(((ACC)[3][_r] - _m) * SCALE);                \
        float _ss = _e0 + _e1 + _e2 + _e3;                              \
        _ss += __shfl_xor(_ss, 1);                                      \
        _ss += __shfl_xor(_ss, 2);                                      \
        _ss += __shfl_xor(_ss, 4);                                      \
        _ss += __shfl_xor(_ss, 8);                                      \
        float _iv = 1.f / _ss;                                          \
        (ACC)[0][_r] = _e0 * _iv; (ACC)[1][_r] = _e1 * _iv;             \
        (ACC)[2][_r] = _e2 * _iv; (ACC)[3][_r] = _e3 * _iv;             \
    }                                                                   \
    _Pragma("unroll")                                                   \
    for (int _nt = 0; _nt < 4; ++_nt) {                                 \
        int _k = l15 + 16 * _nt;                                        \
        *(float4*)(outS + (size_t)_k * 256 + (QOFF)) =                  \
            make_float4((ACC)[_nt][0], (ACC)[_nt][1],                   \
                        (ACC)[_nt][2], (ACC)[_nt][3]);                  \
    }                                                                   \
} while (0)

// -------- kernel 1 (8 blocks): pre-split W1T(+bias), W2T, G (hi/lo), g --------
__global__ __launch_bounds__(256) void precompute_kernel(
    const float* __restrict__ W1, const float* __restrict__ b1,
    const float* __restrict__ W2,
    const float* __restrict__ W3, const float* __restrict__ b3,
    char* __restrict__ ws)
{
    __shared__ float W3t[128][64];
    const int tid = threadIdx.x, blk = blockIdx.x;
    for (int e = tid; e < 8192; e += 256) W3t[e & 127][e >> 7] = W3[e];
    __syncthreads();

    unsigned short* gh = (unsigned short*)(ws + WS_GH);
    unsigned short* gl = (unsigned short*)(ws + WS_GL);
    for (int idx = blk * 512 + tid; idx < blk * 512 + 512; idx += 256) {
        int r = idx >> 6, k = idx & 63;
        float a = 0.f;
        for (int d = 0; d < 128; ++d) a = fmaf(W3t[d][r], W3t[d][k], a);
        unsigned h = f2bf(a);
        gh[idx] = (unsigned short)h;
        gl[idx] = (unsigned short)f2bf(a - bfhi(h));
    }
    if (blk == 0) {
        unsigned short* w1h = (unsigned short*)(ws + WS_W1H);
        unsigned short* w1l = (unsigned short*)(ws + WS_W1L);
        unsigned short* w2h = (unsigned short*)(ws + WS_W2H);
        unsigned short* w2l = (unsigned short*)(ws + WS_W2L);
        for (int e = tid; e < 4096; e += 256) {
            int j = e >> 6, i = e & 63;
            float v1 = (j < 42) ? W1[e] : ((j == 42) ? b1[i] : 0.f);
            unsigned u = __float_as_uint(v1);
            w1h[i * 64 + j] = (unsigned short)(u >> 16);
            float r1 = v1 - __uint_as_float(u & 0xffff0000u);
            w1l[i * 64 + j] = (unsigned short)(__float_as_uint(r1) >> 16);
            float v2 = W2[e];
            u = __float_as_uint(v2);
            w2h[i * 64 + j] = (unsigned short)(u >> 16);
            float r2 = v2 - __uint_as_float(u & 0xffff0000u);
            w2l[i * 64 + j] = (unsigned short)(__float_as_uint(r2) >> 16);
        }
        if (tid < 64) {
            float a = 0.f;
            for (int d = 0; d < 128; ++d) a = fmaf(W3t[d][tid], b3[d], a);
            ((float*)(ws + WS_g))[tid] = a;
        }
    }
}

// -------- kernel 2: fused MFMA, 1 scene/block, reg A-frags + shared B-frags --------
__global__ __launch_bounds__(256, 2) void cam_mfma_kernel(
    const float* __restrict__ input_poses, const float* __restrict__ target_poses,
    const float* __restrict__ b2, const char* __restrict__ ws, float* __restrict__ out)
{
    __shared__ __align__(16) char smem[LDS_BYTES];
    const int tid = threadIdx.x, lane = tid & 63, w = tid >> 6, s = blockIdx.x;
    const int l15 = lane & 15, g = lane >> 4, q4 = g << 2;
    const int swz = (l15 & 7) << 4;
    const int aoff0 = l15 * 128 + ((g << 4) ^ swz);           // B-plane frag offsets
    const int aoff1 = l15 * 128 + ((64 + (g << 4)) ^ swz);
    const int hb00 = l15 * 256 + ((32 * g) ^ swz);            // H plane chunks
    const int hb01 = l15 * 256 + ((32 * g + 16) ^ swz);
    const int hb10 = l15 * 256 + ((32 * g + 128) ^ swz);
    const int hb11 = l15 * 256 + ((32 * g + 128 + 16) ^ swz);

    char* ZK = smem + L_G;
    char* HA = smem + L_XH + (w << 13);          // H plane A (4K)
    char* HB = HA + 4096;                        // H plane B (4K)
    float* ckF = (float*)(smem + L_CK);

    // ---- stage W1T and G planes from pre-split ws (u32 copies, swizzled) ----
    {
        const unsigned* srcW1 = (const unsigned*)(ws + WS_W1H);
        const unsigned* srcG  = (const unsigned*)(ws + WS_GH);
#pragma unroll
        for (int half = 0; half < 2; ++half) {
            for (int e = tid; e < 2048; e += 256) {
                int n = e >> 5, cu = e & 31;
                int byte = n * 128 + ((cu * 4) ^ ((n & 7) << 4));
                *(unsigned*)(smem + L_W1T + half * 8192 + byte) = srcW1[half * 2048 + e];
                *(unsigned*)(smem + L_G   + half * 8192 + byte) = srcG [half * 2048 + e];
            }
        }
    }
    // resident W2T fragments + b2 + g
    short8 w2h[2][4], w2l[2][4];
#pragma unroll
    for (int ks = 0; ks < 2; ++ks)
#pragma unroll
        for (int nt = 0; nt < 4; ++nt) {
            const int off = (l15 + 16 * nt) * 128 + (g << 4) + 64 * ks;
            w2h[ks][nt] = *(const short8*)(ws + WS_W2H + off);
            w2l[ks][nt] = *(const short8*)(ws + WS_W2L + off);
        }
    float b2v[4], gw[4];
#pragma unroll
    for (int nt = 0; nt < 4; ++nt) {
        b2v[nt] = b2[l15 + 16 * nt];
        gw[nt]  = ((const float*)(ws + WS_g))[l15 + 16 * nt];
    }

    short8 Ah0, Al0, Ah1, Al1;
    // key-tile A-frags (register-only; fills staging shadow)
    pe_frags(Ah0, Al0, Ah1, Al1, input_poses + ((size_t)(s * 64 + 16 * w + l15)) * 16, g);
    __syncthreads();   // barrier 0: W1T/G staged

    // ================= key tile (wave w -> keys 16w..16w+15) =================
    f32x4 zacc[4];
    {
        f32x4 acc[4];
#pragma unroll
        for (int nt = 0; nt < 4; ++nt) acc[nt] = mk4(0.f);
        GEMM6_LDS(acc, Ah0, Al0, Ah1, Al1, smem + L_W1T);   // L1 (bias via K-col)
        RELU4(acc);
        STORE_H(HA, acc);                                    // H1

        READ_A(HA, Ah0, Al0, Ah1, Al1);
#pragma unroll
        for (int nt = 0; nt < 4; ++nt) acc[nt] = mk4(b2v[nt]);
        GEMM6_REG(acc, Ah0, Al0, Ah1, Al1, w2h, w2l);        // L2
        RELU4(acc);

        // ck[key] = g . h2k
#pragma unroll
        for (int r = 0; r < 4; ++r) {
            float t = acc[0][r] * gw[0];
            t = fmaf(acc[1][r], gw[1], t);
            t = fmaf(acc[2][r], gw[2], t);
            t = fmaf(acc[3][r], gw[3], t);
            t += __shfl_xor(t, 1);
            t += __shfl_xor(t, 2);
            t += __shfl_xor(t, 4);
            t += __shfl_xor(t, 8);
            if (l15 == 0) ckF[16 * w + q4 + r] = t;
        }
        STORE_H(HA, acc);                                    // H2

        READ_A(HA, Ah0, Al0, Ah1, Al1);
#pragma unroll
        for (int nt = 0; nt < 4; ++nt) zacc[nt] = mk4(0.f);
        GEMM6_LDS(zacc, Ah0, Al0, Ah1, Al1, smem + L_G);     // Zk = H2k @ G
    }
    __syncthreads();   // barrier 1: all G reads + ck writes done

    // scatter Zk tile over G (trunc hi/lo), swizzled B-plane layout
#pragma unroll
    for (int nt = 0; nt < 4; ++nt) {
#pragma unroll
        for (int r = 0; r < 4; ++r) {
            int row = 16 * w + q4 + r;
            int byte = row * 128 + (((l15 + 16 * nt) * 2) ^ ((row & 7) << 4));
            float zv = zacc[nt][r];
            unsigned u = __float_as_uint(zv);
            *(unsigned short*)(ZK + byte) = (unsigned short)(u >> 16);
            float res = zv - __uint_as_float(u & 0xffff0000u);
            *(unsigned short*)(ZK + 8192 + byte) = (unsigned short)(__float_as_uint(res) >> 16);
        }
    }
    __syncthreads();   // barrier 2: Zk + ck visible
    float ckreg[4];
#pragma unroll
    for (int nt = 0; nt < 4; ++nt) ckreg[nt] = ckF[l15 + 16 * nt];

    // ========= query tile pairs: wave w does tiles (8p+w, 8p+4+w), p=0,1 =========
    float* outS = out + (size_t)s * 16384;
    short8 Bh0, Bl0, Bh1, Bl1;
#pragma unroll 1
    for (int p = 0; p < 2; ++p) {
        f32x4 accA[4], accB[4];
        // PE -> A-frags in registers (no LDS round trip)
        pe_frags(Ah0, Al0, Ah1, Al1,
                 target_poses + ((size_t)(s * 256 + (p * 8 + w) * 16 + l15)) * 16, g);
        pe_frags(Bh0, Bl0, Bh1, Bl1,
                 target_poses + ((size_t)(s * 256 + (p * 8 + 4 + w) * 16 + l15)) * 16, g);

        // ---- L1 both tiles, shared B-frags ----
#pragma unroll
        for (int nt = 0; nt < 4; ++nt) { accA[nt] = mk4(0.f); accB[nt] = mk4(0.f); }
        GEMM6_LDS_PAIR(accA, Ah0, Al0, Ah1, Al1, accB, Bh0, Bl0, Bh1, Bl1, smem + L_W1T);
        RELU4(accA); RELU4(accB);
        STORE_H(HA, accA);
        STORE_H(HB, accB);

        // ---- L2 both tiles (B in registers) ----
        READ_A(HA, Ah0, Al0, Ah1, Al1);
        READ_A(HB, Bh0, Bl0, Bh1, Bl1);
#pragma unroll
        for (int nt = 0; nt < 4; ++nt) { accA[nt] = mk4(b2v[nt]); accB[nt] = mk4(b2v[nt]); }
        GEMM6_REG(accA, Ah0, Al0, Ah1, Al1, w2h, w2l);
        GEMM6_REG(accB, Bh0, Bl0, Bh1, Bl1, w2h, w2l);
        RELU4(accA); RELU4(accB);
        STORE_H(HA, accA);
        STORE_H(HB, accB);

        // ---- scores both tiles, shared Zk B-frags ----
        READ_A(HA, Ah0, Al0, Ah1, Al1);
        READ_A(HB, Bh0, Bl0, Bh1, Bl1);
#pragma unroll
        for (int nt = 0; nt < 4; ++nt) { accA[nt] = mk4(ckreg[nt]); accB[nt] = mk4(ckreg[nt]); }
        GEMM6_LDS_PAIR(accA, Ah0, Al0, Ah1, Al1, accB, Bh0, Bl0, Bh1, Bl1, smem + L_G);

        // ---- softmax + transposed stores ----
        const int qoffA = (p * 8 + w) * 16 + q4;
        const int qoffB = (p * 8 + 4 + w) * 16 + q4;
        SOFTMAX_STORE(accA, qoffA);
        SOFTMAX_STORE(accB, qoffB);
    }
}

extern "C" void kernel_launch(void* const* d_in, const int* in_sizes, int n_in,
                              void* d_out, int out_size, void* d_ws, size_t ws_size,
                              hipStream_t stream) {
    const float* input_poses  = (const float*)d_in[0];
    const float* target_poses = (const float*)d_in[1];
    const float* W1 = (const float*)d_in[2];
    const float* b1 = (const float*)d_in[3];
    const float* W2 = (const float*)d_in[4];
    const float* b2 = (const float*)d_in[5];
    const float* W3 = (const float*)d_in[6];
    const float* b3 = (const float*)d_in[7];
    float* out = (float*)d_out;
    char* ws = (char*)d_ws;   // uses 49408 bytes

    precompute_kernel<<<dim3(8), dim3(256), 0, stream>>>(W1, b1, W2, W3, b3, ws);
    cam_mfma_kernel<<<dim3(1024), dim3(256), 0, stream>>>(
        input_poses, target_poses, b2, ws, out);
}